// Round 1
// baseline (913.397 us; speedup 1.0000x reference)
//
#include <hip/hip_runtime.h>

typedef short short8_t __attribute__((ext_vector_type(8)));
typedef __bf16 bf16x8  __attribute__((ext_vector_type(8)));
typedef float f32x4    __attribute__((ext_vector_type(4)));

union FragU { short4 h[2]; short8_t s; bf16x8 b; };

__device__ __forceinline__ unsigned short bf16rne(float f){
  unsigned u = __float_as_uint(f);
  unsigned r = u + 0x7FFFu + ((u >> 16) & 1u);
  return (unsigned short)(r >> 16);
}
__device__ __forceinline__ float bf2f(unsigned short h){
  return __uint_as_float(((unsigned)h) << 16);
}

#define MFMA(A,B,C) __builtin_amdgcn_mfma_f32_16x16x32_bf16((A),(B),(C),0,0,0)

// ---- ws byte offsets ----
#define OFF_SUM    0        // 256 f32 column sums
#define OFF_SUMSQ  1024     // 256 f32 column sumsq
#define OFF_SCALE  2048     // 256 f32 (floats idx 512)
#define OFF_SHIFT  3072     // 256 f32 (floats idx 768)
#define OFF_NORMA  4096     // 16 f32  (floats idx 1024)
#define OFF_B2P    4160     // 128 f32 (floats idx 1040)
#define OFF_W1T    8192     // hi 65536 B, lo 65536 B   [kc4][nt16][lane64][e8] bf16
#define OFF_W2T    139264   // hi 65536 B, lo 65536 B   [kc8][nt8][lane64][e8]  (W2' = scale-folded)
#define OFF_WE     270336   // 10 experts x (We1hi 16384 + We1lo 16384 + We2 2048)
#define WE_STRIDE  34816
#define OFF_ATTRT  618496   // 4096 B [kc4][nt1][lane64][e8]

// ---------------- K0: weight prep (frag-major, hi/lo split), zero stats, normA ----------------
__global__ __launch_bounds__(256) void k_prep(const float* __restrict__ W1,
                                              const float* __restrict__ We1,
                                              const float* __restrict__ We2,
                                              const float* __restrict__ attr,
                                              char* __restrict__ ws){
  int gid = blockIdx.x * 256 + threadIdx.x;
  float* wsf = (float*)ws;
  if (gid < 512) wsf[gid] = 0.f;                       // zero gsum/gsumsq
  if (blockIdx.x == 0 && threadIdx.x < 16){            // normA
    float s = 0.f;
    if (threadIdx.x < 10){
      const float* a = attr + threadIdx.x * 128;
      for (int e = 0; e < 128; ++e) s += a[e] * a[e];
    }
    wsf[OFF_NORMA/4 + threadIdx.x] = s;
  }
  int idx = gid;
  if (idx < 32768){                                    // W1T hi/lo
    int i = idx & 7, l = (idx >> 3) & 63, nt = (idx >> 9) & 15, kc = idx >> 13;
    int k = kc*32 + ((i >> 2) << 4) + ((l >> 4) << 2) + (i & 3);
    int n = nt*16 + (l & 15);
    float v = (k < 100) ? W1[k*256 + n] : 0.f;
    unsigned short hi = bf16rne(v);
    unsigned short lo = bf16rne(v - bf2f(hi));
    ((unsigned short*)(ws + OFF_W1T))[idx] = hi;
    ((unsigned short*)(ws + OFF_W1T + 65536))[idx] = lo;
    return;
  }
  idx -= 32768;
  if (idx < 81920){                                    // We1T hi/lo per expert
    int ke = idx >> 13, sub = idx & 8191;
    int i = sub & 7, l = (sub >> 3) & 63, nt = (sub >> 9) & 3, kc = sub >> 11;
    int k = kc*32 + ((i >> 2) << 4) + ((l >> 4) << 2) + (i & 3);   // e-dim 0..127
    int n = nt*16 + (l & 15);                                      // h-dim 0..63
    float v = We1[ke*8192 + k*64 + n];
    unsigned short hi = bf16rne(v);
    unsigned short lo = bf16rne(v - bf2f(hi));
    char* base = ws + OFF_WE + ke*WE_STRIDE;
    ((unsigned short*)base)[sub] = hi;
    ((unsigned short*)(base + 16384))[sub] = lo;
    return;
  }
  idx -= 81920;
  if (idx < 10240){                                    // We2T plain
    int ke = idx >> 10, sub = idx & 1023;
    int i = sub & 7, l = (sub >> 3) & 63, kc = sub >> 9;
    int k = kc*32 + ((i >> 2) << 4) + ((l >> 4) << 2) + (i & 3);   // h-dim 0..63
    int n = l & 15;                                                // action
    float v = (n < 10) ? We2[ke*640 + k*10 + n] : 0.f;
    ((unsigned short*)(ws + OFF_WE + ke*WE_STRIDE + 32768))[sub] = bf16rne(v);
    return;
  }
  idx -= 10240;
  if (idx < 2048){                                     // attrT plain
    int i = idx & 7, l = (idx >> 3) & 63, kc = idx >> 9;
    int k = kc*32 + ((i >> 2) << 4) + ((l >> 4) << 2) + (i & 3);   // e-dim
    int n = l & 15;
    float v = (n < 10) ? attr[n*128 + k] : 0.f;
    ((unsigned short*)(ws + OFF_ATTRT))[idx] = bf16rne(v);
  }
}

// ---------------- K2: finalize BN stats -> scale/shift ----------------
__global__ void k_finalize(const float* __restrict__ gamma, const float* __restrict__ beta,
                           char* __restrict__ ws){
  int c = threadIdx.x;
  float* f = (float*)ws;
  const float inv = 1.f / 262144.f;
  float mu  = f[c] * inv;
  float var = f[256 + c] * inv - mu * mu;
  float sc  = gamma[c] * rsqrtf(var + 1e-5f);
  f[512 + c] = sc;
  f[768 + c] = beta[c] - mu * sc;
}

// ---------------- K2b: W2' = diag(scale)*W2 (frag-major hi/lo) and b2' ----------------
__global__ __launch_bounds__(256) void k_prep2(const float* __restrict__ W2,
                                               const float* __restrict__ b2,
                                               char* __restrict__ ws){
  float* f = (float*)ws;
  if (blockIdx.x == 128){
    int n = threadIdx.x;
    if (n < 128){
      float s = b2[n];
      for (int k = 0; k < 256; ++k) s += f[768 + k] * W2[k*128 + n];
      f[OFF_B2P/4 + n] = s;
    }
    return;
  }
  int idx = blockIdx.x * 256 + threadIdx.x;            // 0..32767
  int i = idx & 7, l = (idx >> 3) & 63, nt = (idx >> 9) & 7, kc = idx >> 12;
  int k = kc*32 + ((i >> 2) << 4) + ((l >> 4) << 2) + (i & 3);
  int n = nt*16 + (l & 15);
  float v = W2[k*128 + n] * f[512 + k];
  unsigned short hi = bf16rne(v);
  unsigned short lo = bf16rne(v - bf2f(hi));
  ((unsigned short*)(ws + OFF_W2T))[idx] = hi;
  ((unsigned short*)(ws + OFF_W2T + 65536))[idx] = lo;
}

// ---------------- fragment helpers ----------------
// A tile: swizzled row-major bf16, RB = row stride in bytes (pow2 >= 128)
__device__ __forceinline__ bf16x8 afrag(const short* buf, int RB, int row, int kc, int lq){
  int swz = (row & 7) << 4;
  int rb  = row * RB;
  int c0  = kc*64 + lq*8;                // byte col of k-slice
  FragU f;
  f.h[0] = *(const short4*)(buf + ((rb + ( c0       ^ swz)) >> 1));
  f.h[1] = *(const short4*)(buf + ((rb + ((c0 + 32) ^ swz)) >> 1));
  return f.b;
}
__device__ __forceinline__ bf16x8 bfrag(const short* buf, int nt, int l){
  FragU f;
  f.s = *(const short8_t*)(buf + nt*512 + l*8);
  return f.b;
}
__device__ __forceinline__ void astore(short* buf, int RB, int row, int colb, unsigned short v){
  buf[(row*RB + (colb ^ ((row & 7) << 4))) >> 1] = (short)v;
}
__device__ __forceinline__ void stage16(const char* src, short* dst, int n8, int tid){
  const short8_t* s = (const short8_t*)src;
  short8_t* d = (short8_t*)dst;
  for (int i = tid; i < n8; i += 256) d[i] = s[i];
}

// ---------------- main kernel (STATS pass / fused pass) ----------------
template<bool STATS>
__global__ __launch_bounds__(256, 2) void k_main(const float* __restrict__ state,
                                                 const float* __restrict__ b1,
                                                 const float* __restrict__ be1,
                                                 const float* __restrict__ be2,
                                                 char* __restrict__ ws,
                                                 float* __restrict__ out){
  __shared__ __align__(16) short U[32768];   // 64KB phase-union region
  __shared__ __align__(16) short Bs[8192];   // 16KB B staging
  const int tid = threadIdx.x;
  const int w = tid >> 6, l = tid & 63, lq = l >> 4, lr = l & 15;
  const int row0 = blockIdx.x * 64;

  // ---- Phase A: stage state tile (hi / lo) into U[0..8191], U[8192..16383]
  short* A1h = U;
  short* A1l = U + 8192;
  for (int q = tid; q < 1600; q += 256){
    int row = q / 25, kq = q - row*25;
    float4 v = *(const float4*)(state + (size_t)(row0 + row)*100 + kq*4);
    int swz = (row & 7) << 4;
    int off = (row*256 + ((kq*8) ^ swz)) >> 1;
    unsigned short h0 = bf16rne(v.x), h1 = bf16rne(v.y), h2 = bf16rne(v.z), h3 = bf16rne(v.w);
    *(short4*)(A1h + off) = make_short4((short)h0,(short)h1,(short)h2,(short)h3);
    if constexpr (!STATS){
      unsigned short l0 = bf16rne(v.x - bf2f(h0)), l1 = bf16rne(v.y - bf2f(h1));
      unsigned short l2 = bf16rne(v.z - bf2f(h2)), l3 = bf16rne(v.w - bf2f(h3));
      *(short4*)(A1l + off) = make_short4((short)l0,(short)l1,(short)l2,(short)l3);
    }
  }
  for (int q = tid; q < 448; q += 256){      // zero-pad k = 100..127
    int row = q / 7, j = q - row*7;
    int off = (row*256 + ((200 + j*8) ^ ((row & 7) << 4))) >> 1;
    *(short4*)(A1h + off) = make_short4(0,0,0,0);
    if constexpr (!STATS) *(short4*)(A1l + off) = make_short4(0,0,0,0);
  }

  // ---- GEMM1: h = relu(state @ W1 + b1); wave w owns n-tiles w*4..w*4+3
  f32x4 acc1[4][4];
  #pragma unroll
  for (int a = 0; a < 4; ++a)
    #pragma unroll
    for (int b = 0; b < 4; ++b) acc1[a][b] = (f32x4){0.f,0.f,0.f,0.f};

  const char* w1hi = ws + OFF_W1T;
  const char* w1lo = ws + OFF_W1T + 65536;
  for (int kc = 0; kc < 4; ++kc){
    __syncthreads();
    stage16(w1hi + kc*16384, Bs, 1024, tid);
    __syncthreads();
    bf16x8 ah[4], al[4];
    #pragma unroll
    for (int mt = 0; mt < 4; ++mt){
      ah[mt] = afrag(A1h, 256, mt*16 + lr, kc, lq);
      if constexpr (!STATS) al[mt] = afrag(A1l, 256, mt*16 + lr, kc, lq);
    }
    #pragma unroll
    for (int ntl = 0; ntl < 4; ++ntl){
      bf16x8 bh = bfrag(Bs, w*4 + ntl, l);
      #pragma unroll
      for (int mt = 0; mt < 4; ++mt){
        acc1[mt][ntl] = MFMA(ah[mt], bh, acc1[mt][ntl]);
        if constexpr (!STATS) acc1[mt][ntl] = MFMA(al[mt], bh, acc1[mt][ntl]);
      }
    }
    if constexpr (!STATS){
      __syncthreads();
      stage16(w1lo + kc*16384, Bs, 1024, tid);
      __syncthreads();
      #pragma unroll
      for (int ntl = 0; ntl < 4; ++ntl){
        bf16x8 bl = bfrag(Bs, w*4 + ntl, l);
        #pragma unroll
        for (int mt = 0; mt < 4; ++mt) acc1[mt][ntl] = MFMA(ah[mt], bl, acc1[mt][ntl]);
      }
    }
  }

  float b1v[4];
  #pragma unroll
  for (int ntl = 0; ntl < 4; ++ntl) b1v[ntl] = b1[(w*4 + ntl)*16 + lr];

  if constexpr (STATS){
    float* gsum = (float*)ws;
    float* gsq  = (float*)(ws + OFF_SUMSQ);
    #pragma unroll
    for (int ntl = 0; ntl < 4; ++ntl){
      float s = 0.f, q = 0.f;
      #pragma unroll
      for (int mt = 0; mt < 4; ++mt)
        #pragma unroll
        for (int r = 0; r < 4; ++r){
          float h = fmaxf(acc1[mt][ntl][r] + b1v[ntl], 0.f);
          s += h; q += h*h;
        }
      s += __shfl_xor(s, 16); s += __shfl_xor(s, 32);
      q += __shfl_xor(q, 16); q += __shfl_xor(q, 32);
      if (l < 16){
        int col = (w*4 + ntl)*16 + lr;
        atomicAdd(&gsum[col], s);
        atomicAdd(&gsq[col], q);
      }
    }
    return;
  } else {
    // ---- write h (hi/lo) over U: Hh = U[0..16383], Hl = U[16384..32767]
    __syncthreads();                         // all GEMM1 A1 reads done
    short* Hh = U;
    short* Hl = U + 16384;
    #pragma unroll
    for (int ntl = 0; ntl < 4; ++ntl){
      int colb = ((w*4 + ntl)*16 + lr) * 2;
      #pragma unroll
      for (int mt = 0; mt < 4; ++mt)
        #pragma unroll
        for (int r = 0; r < 4; ++r){
          int row = mt*16 + lq*4 + r;
          float h = fmaxf(acc1[mt][ntl][r] + b1v[ntl], 0.f);
          unsigned short hi = bf16rne(h);
          unsigned short lo = bf16rne(h - bf2f(hi));
          astore(Hh, 512, row, colb, hi);
          astore(Hl, 512, row, colb, lo);
        }
    }

    // ---- GEMM2: enc = tanh(h @ W2' + b2'); wave w owns n-tiles w*2, w*2+1
    f32x4 acc2[4][2];
    #pragma unroll
    for (int a = 0; a < 4; ++a){ acc2[a][0] = (f32x4){0.f,0.f,0.f,0.f}; acc2[a][1] = (f32x4){0.f,0.f,0.f,0.f}; }
    const char* w2hi = ws + OFF_W2T;
    const char* w2lo = ws + OFF_W2T + 65536;
    for (int kc = 0; kc < 8; ++kc){
      __syncthreads();
      stage16(w2hi + kc*8192, Bs, 512, tid);
      stage16(w2lo + kc*8192, Bs + 4096, 512, tid);
      __syncthreads();
      bf16x8 ah[4], al[4];
      #pragma unroll
      for (int mt = 0; mt < 4; ++mt){
        ah[mt] = afrag(Hh, 512, mt*16 + lr, kc, lq);
        al[mt] = afrag(Hl, 512, mt*16 + lr, kc, lq);
      }
      #pragma unroll
      for (int ntl = 0; ntl < 2; ++ntl){
        bf16x8 bh = bfrag(Bs, w*2 + ntl, l);
        bf16x8 bl = bfrag(Bs + 4096, w*2 + ntl, l);
        #pragma unroll
        for (int mt = 0; mt < 4; ++mt){
          acc2[mt][ntl] = MFMA(ah[mt], bh, acc2[mt][ntl]);
          acc2[mt][ntl] = MFMA(al[mt], bh, acc2[mt][ntl]);
          acc2[mt][ntl] = MFMA(ah[mt], bl, acc2[mt][ntl]);
        }
      }
    }

    // ---- enc (hi/lo) into U[0..8191]/U[8192..16383]; attrT into U[16384..18431]
    const float* b2p = (const float*)(ws + OFF_B2P);
    __syncthreads();                         // all GEMM2 h reads done
    short* Eh = U;
    short* El = U + 8192;
    #pragma unroll
    for (int ntl = 0; ntl < 2; ++ntl){
      int col = (w*2 + ntl)*16 + lr;
      float bb = b2p[col];
      #pragma unroll
      for (int mt = 0; mt < 4; ++mt)
        #pragma unroll
        for (int r = 0; r < 4; ++r){
          int row = mt*16 + lq*4 + r;
          float x = acc2[mt][ntl][r] + bb;
          x = fminf(fmaxf(x, -30.f), 30.f);
          float e = __expf(-2.f * x);
          float t = (1.f - e) / (1.f + e);
          unsigned short hi = bf16rne(t);
          unsigned short lo = bf16rne(t - bf2f(hi));
          astore(Eh, 256, row, col*2, hi);
          astore(El, 256, row, col*2, lo);
        }
    }
    stage16(ws + OFF_ATTRT, U + 16384, 256, tid);
    __syncthreads();

    // ---- enc-hi fragments to registers; normE; distance GEMM
    bf16x8 efh[4][4];
    #pragma unroll
    for (int mt = 0; mt < 4; ++mt)
      #pragma unroll
      for (int kc = 0; kc < 4; ++kc) efh[mt][kc] = afrag(Eh, 256, mt*16 + lr, kc, lq);

    float* normE = (float*)(U + 23552);
    #pragma unroll
    for (int mt = 0; mt < 4; ++mt){
      float s = 0.f;
      #pragma unroll
      for (int kc = 0; kc < 4; ++kc){
        bf16x8 lo8 = afrag(El, 256, mt*16 + lr, kc, lq);
        #pragma unroll
        for (int e = 0; e < 8; ++e){
          float v = (float)efh[mt][kc][e] + (float)lo8[e];
          s += v * v;
        }
      }
      s += __shfl_xor(s, 16); s += __shfl_xor(s, 32);
      if (w == 0 && l < 16) normE[mt*16 + lr] = s;
    }

    const short* attrT = U + 16384;
    f32x4 accd = (f32x4){0.f,0.f,0.f,0.f};
    #pragma unroll
    for (int kc = 0; kc < 4; ++kc)
      accd = MFMA(efh[w][kc], bfrag(attrT + kc*512, 0, l), accd);

    // ---- expert loop: eh = relu(enc@We1_k + be1_k); hab = eh@We2_k
    short* ehT  = U + 18432;   // [64][64] bf16 swizzled
    short* we2T = U + 22528;   // 1024 shorts
    const char* webase = ws + OFF_WE;
    f32x4 hab[10];
    #pragma unroll
    for (int ke = 0; ke < 10; ++ke) hab[ke] = (f32x4){0.f,0.f,0.f,0.f};

    #pragma unroll
    for (int ke = 0; ke < 10; ++ke){
      const char* wb = webase + ke*WE_STRIDE;
      __syncthreads();                       // prev E2 reads done; Bs free
      stage16(wb, Bs, 1024, tid);            // We1T hi
      stage16(wb + 32768, we2T, 128, tid);   // We2T
      __syncthreads();
      f32x4 acce[4];
      #pragma unroll
      for (int mt = 0; mt < 4; ++mt) acce[mt] = (f32x4){0.f,0.f,0.f,0.f};
      #pragma unroll
      for (int kc = 0; kc < 4; ++kc){
        bf16x8 bh = bfrag(Bs + kc*2048, w, l);
        #pragma unroll
        for (int mt = 0; mt < 4; ++mt) acce[mt] = MFMA(efh[mt][kc], bh, acce[mt]);
        #pragma unroll
        for (int mt = 0; mt < 4; ++mt){
          bf16x8 el8 = afrag(El, 256, mt*16 + lr, kc, lq);
          acce[mt] = MFMA(el8, bh, acce[mt]);
        }
      }
      __syncthreads();
      stage16(wb + 16384, Bs, 1024, tid);    // We1T lo
      __syncthreads();
      #pragma unroll
      for (int kc = 0; kc < 4; ++kc){
        bf16x8 bl = bfrag(Bs + kc*2048, w, l);
        #pragma unroll
        for (int mt = 0; mt < 4; ++mt) acce[mt] = MFMA(efh[mt][kc], bl, acce[mt]);
      }
      {
        int col = w*16 + lr;                 // wave w owns eh cols w*16..+15
        float bev = be1[ke*64 + col];
        #pragma unroll
        for (int mt = 0; mt < 4; ++mt)
          #pragma unroll
          for (int r = 0; r < 4; ++r){
            int row = mt*16 + lq*4 + r;
            float v = fmaxf(acce[mt][r] + bev, 0.f);
            astore(ehT, 128, row, col*2, bf16rne(v));
          }
      }
      __syncthreads();
      #pragma unroll
      for (int kc2 = 0; kc2 < 2; ++kc2){     // E2: wave w owns rows w*16..+15
        bf16x8 af = afrag(ehT, 128, w*16 + lr, kc2, lq);
        bf16x8 bf2 = bfrag(we2T + kc2*512, 0, l);
        hab[ke] = MFMA(af, bf2, hab[ke]);
      }
    }

    // ---- distances -> softmax -> weighted output (wave w owns rows w*16..+15)
    const float* normAp = (const float*)(ws + OFF_NORMA);
    float nA = (lr < 10) ? normAp[lr] : 0.f;
    float be2c[10];
    #pragma unroll
    for (int ke = 0; ke < 10; ++ke) be2c[ke] = (lr < 10) ? be2[ke*10 + lr] : 0.f;
    __syncthreads();
    #pragma unroll
    for (int r = 0; r < 4; ++r){
      int row = w*16 + lq*4 + r;
      float d2 = normE[row] + nA - 2.f * accd[r];
      float dist = sqrtf(fmaxf(d2, 0.f));
      float logit = (lr < 10) ? (-2.f * dist) : -3.0e38f;
      float m = logit;
      #pragma unroll
      for (int o = 1; o < 16; o <<= 1) m = fmaxf(m, __shfl_xor(m, o));
      float e = __expf(logit - m);
      float ssum = e;
      #pragma unroll
      for (int o = 1; o < 16; o <<= 1) ssum += __shfl_xor(ssum, o);
      float sv = e / ssum;
      float acc_o = 0.f;
      #pragma unroll
      for (int ke = 0; ke < 10; ++ke){
        float sk = __shfl(sv, (l & 48) | ke);
        acc_o += (hab[ke][r] + be2c[ke]) * sk;
      }
      if (lr < 10) out[(size_t)(row0 + row)*10 + lr] = acc_o;
    }
  }
}

extern "C" void kernel_launch(void* const* d_in, const int* in_sizes, int n_in,
                              void* d_out, int out_size, void* d_ws, size_t ws_size,
                              hipStream_t stream){
  const float* state = (const float*)d_in[0];
  const float* W1    = (const float*)d_in[1];
  const float* b1    = (const float*)d_in[2];
  const float* gamma = (const float*)d_in[3];
  const float* beta  = (const float*)d_in[4];
  const float* W2    = (const float*)d_in[5];
  const float* b2    = (const float*)d_in[6];
  const float* We1   = (const float*)d_in[7];
  const float* be1   = (const float*)d_in[8];
  const float* We2   = (const float*)d_in[9];
  const float* be2   = (const float*)d_in[10];
  const float* attr  = (const float*)d_in[11];
  char* ws  = (char*)d_ws;
  float* out = (float*)d_out;

  k_prep<<<496, 256, 0, stream>>>(W1, We1, We2, attr, ws);
  k_main<true><<<4096, 256, 0, stream>>>(state, b1, nullptr, nullptr, ws, nullptr);
  k_finalize<<<1, 256, 0, stream>>>(gamma, beta, ws);
  k_prep2<<<129, 256, 0, stream>>>(W2, b2, ws);
  k_main<false><<<4096, 256, 0, stream>>>(state, b1, be1, be2, ws, out);
}